// Round 15
// baseline (167.202 us; speedup 1.0000x reference)
//
#include <hip/hip_runtime.h>

// MaskTypeProbabilitiesLayer R15: discriminating split.
//   K1: PURE READ PROBE — block-per-row, register-only first5/first6 reduce,
//       zero stores in the hot loop (8 B/block at end). Measures the input
//       read stream in isolation.
//   K2: fused gather+emit, copy-regime (grid-stride, no LDS, no barriers):
//       reads gt dword straight from input (LLC-hot after K1), writes 66 MB
//       dense int4.
// Falsified so far for the 2.0-2.4 TB/s read ceiling: occupancy, access
// pattern, per-thread MLP, nt/cache-allocation. Writes proven 6.8 TB/s.
//
// Bit-packed: TYPE_TABLE[0]=0x02 [1]=0x06 [2]=0x10 [3]=0xF8 [7]=0x80;
//   NO_TIMESIGN=0x20 NO_TEMPO=0x40 FULL=0xF8.

#define SEQ_L 2048
#define NF 11
#define BATCH 1024
#define K2_GRID 4096
#define K2_PASSES 4     // 4096*256*4 = 4,194,304 out int4 chunks

// ---- K1: firsts only (pure read + reduce) ----
__global__ __launch_bounds__(512)
void firsts_kernel(const int* __restrict__ in,
                   unsigned* __restrict__ first5, unsigned* __restrict__ first6) {
    __shared__ unsigned s_f5, s_f6;
    const int b   = blockIdx.x;
    const int tid = threadIdx.x;
    if (tid == 0) { s_f5 = 0xFFFFFFFFu; s_f6 = 0xFFFFFFFFu; }
    __syncthreads();

    const int4* rowv = (const int4*)(in + (size_t)b * SEQ_L * NF);
    unsigned f5 = 0xFFFFFFFFu, f6 = 0xFFFFFFFFu;
    #pragma unroll
    for (int p = 0; p < 11; ++p) {
        const int i4 = tid + p * 512;          // 0..5631, lane-dense
        const int4 v = rowv[i4];
        const int j  = i4 * 4;
        const int mi  = (j + 10) / 11;         // at most one multiple of 11 in [j,j+4)
        const int pos = mi * 11 - j;           // 0..10
        if (pos < 4) {
            const int gv = (pos == 0) ? v.x : (pos == 1) ? v.y
                         : (pos == 2) ? v.z : v.w;
            if (gv == 5) f5 = min(f5, (unsigned)mi);
            if (gv == 6) f6 = min(f6, (unsigned)mi);
        }
    }
    #pragma unroll
    for (int off = 32; off >= 1; off >>= 1) {
        f5 = min(f5, (unsigned)__shfl_xor((int)f5, off, 64));
        f6 = min(f6, (unsigned)__shfl_xor((int)f6, off, 64));
    }
    if ((tid & 63) == 0) {
        if (f5 != 0xFFFFFFFFu) atomicMin(&s_f5, f5);
        if (f6 != 0xFFFFFFFFu) atomicMin(&s_f6, f6);
    }
    __syncthreads();
    if (tid == 0) { first5[b] = s_f5; first6[b] = s_f6; }
}

// ---- K2: fused gather + dense emit (copy regime) ----
__global__ __launch_bounds__(256)
void emit_kernel(const int* __restrict__ in, const unsigned* __restrict__ first5,
                 const unsigned* __restrict__ first6, int* __restrict__ out) {
    const int base = blockIdx.x * 256 + threadIdx.x;
    const unsigned long long pack = 0x80000000F8100602ULL;
    int4* outv = (int4*)out;
    #pragma unroll
    for (int p = 0; p < K2_PASSES; ++p) {
        const int c    = base + p * (K2_GRID * 256);  // 0..4194303, lane-dense
        const int tg   = c >> 1;                      // global position
        const int half = c & 1;
        const int row  = tg >> 11;                    // wave-uniform (4096 chunks/row)
        const int t    = tg & (SEQ_L - 1);
        // gt gather straight from input (LLC-hot after K1); lane pairs share.
        const int gv = in[(size_t)row * (SEQ_L * NF) + t * NF];
        unsigned m;
        if (gv >= 4 && gv <= 6) {
            const unsigned idx = (unsigned)((t + 1 < SEQ_L - 1) ? (t + 1) : (SEQ_L - 1));
            m = (first5[row] > idx) ? 0x20u : ((first6[row] > idx) ? 0x40u : 0xF8u);
        } else {
            const int gc = gv < 0 ? 0 : (gv > 8 ? 8 : gv);
            m = (gc >= 8) ? 0u : (unsigned)((pack >> (gc * 8)) & 0xFFu);
        }
        const unsigned nib = half ? (m >> 4) : m;
        int4 w;
        w.x = (int)((nib >> 0) & 1u);
        w.y = (int)((nib >> 1) & 1u);
        w.z = (int)((nib >> 2) & 1u);
        w.w = (int)((nib >> 3) & 1u);
        outv[c] = w;
    }
}

extern "C" void kernel_launch(void* const* d_in, const int* in_sizes, int n_in,
                              void* d_out, int out_size, void* d_ws, size_t ws_size,
                              hipStream_t stream) {
    const int* in = (const int*)d_in[0];
    int* out = (int*)d_out;

    // ws: [first5: 1024 u32][first6: 1024 u32]
    unsigned* first5 = (unsigned*)d_ws;
    unsigned* first6 = first5 + BATCH;

    firsts_kernel<<<BATCH, 512, 0, stream>>>(in, first5, first6);
    emit_kernel<<<K2_GRID, 256, 0, stream>>>(in, first5, first6, out);
}

// Round 16
// 155.343 us; speedup vs baseline: 1.0763x; 1.0763x over previous
//
#include <hip/hip_runtime.h>

// MaskTypeProbabilitiesLayer R16: 2-row software pipeline to overlap the
// write stream (6.8 TB/s path) under the read stream (empirically pinned at
// ~2.4 TB/s line-service on this harness's restored input — R6..R15 all fit).
//   gt = in[b,t,0]; base = TYPE_TABLE[gt]; gt in {4,5,6} -> dynamic mask from
//   first-occurrence of 5 / 6 vs idx = min(t+1, 2047).
// Bit-packed: TYPE_TABLE[0]=0x02 [1]=0x06 [2]=0x10 [3]=0xF8 [7]=0x80;
//   NO_TIMESIGN=0x20 NO_TEMPO=0x40 FULL=0xF8.
//
// Ledger: R6 55us | R7 occ:neutral | R8 dense:neutral | R9 dense-stores ~50 |
// R10 split:neutral | R11 sched_barrier:neutral | R12 global-atomics 340 |
// R14 nt:neutral | R15 probe: pure read = ~38us => read-service ceiling.
// Model: reads 92MB/2.4 = 38us, writes 66MB/6.8 = 10us; serial 48-50 (now);
// pipelined floor ~= 38-41us kernel.

#define SEQ_L 2048
#define NF 11
#define BLOCK 512
#define PASSES 11                    // 5632 int4 per row / 512 threads
#define OPASS 8                      // 4096 out-int4 per row / 512 threads

__device__ __forceinline__ void emit_row(const int* s_gt, unsigned first5,
                                         unsigned first6, int4* orowv, int tid) {
    const unsigned long long pack = 0x80000000F8100602ULL;
    #pragma unroll
    for (int k = 0; k < OPASS; ++k) {
        const int c    = tid + k * BLOCK;  // 0..4095, lane-dense
        const int t    = c >> 1;
        const int half = c & 1;
        const int gv   = s_gt[t];          // 2-way LDS aliasing: free
        unsigned m;
        if (gv >= 4 && gv <= 6) {
            const unsigned idx = (unsigned)((t + 1 < SEQ_L - 1) ? (t + 1) : (SEQ_L - 1));
            m = (first5 > idx) ? 0x20u : ((first6 > idx) ? 0x40u : 0xF8u);
        } else {
            const int gc = gv < 0 ? 0 : (gv > 8 ? 8 : gv);
            m = (gc >= 8) ? 0u : (unsigned)((pack >> (gc * 8)) & 0xFFu);
        }
        const unsigned nib = half ? (m >> 4) : m;
        int4 w;
        w.x = (int)((nib >> 0) & 1u);
        w.y = (int)((nib >> 1) & 1u);
        w.z = (int)((nib >> 2) & 1u);
        w.w = (int)((nib >> 3) & 1u);
        orowv[c] = w;                      // fire-and-forget
    }
}

__global__ __launch_bounds__(BLOCK)
void mask_type_prob_kernel(const int* __restrict__ in, int* __restrict__ out) {
    __shared__ int s_gt[2][SEQ_L];
    __shared__ unsigned s_f[4];            // f5_0, f6_0, f5_1, f6_1

    const int tid = threadIdx.x;
    const int b0  = blockIdx.x * 2;
    const int b1  = b0 + 1;

    if (tid < 4) s_f[tid] = 0xFFFFFFFFu;
    __syncthreads();

    const int4* row0 = (const int4*)(in + (size_t)b0 * SEQ_L * NF);
    const int4* row1 = (const int4*)(in + (size_t)b1 * SEQ_L * NF);

    // ---- Row 0: read + reduce ----
    unsigned f5 = 0xFFFFFFFFu, f6 = 0xFFFFFFFFu;
    #pragma unroll
    for (int p = 0; p < PASSES; ++p) {
        const int i4 = tid + p * BLOCK;
        const int4 v = row0[i4];
        const int j  = i4 * 4;
        const int mi  = (j + 10) / 11;     // at most one multiple of 11 in [j,j+4)
        const int pos = mi * 11 - j;
        if (pos < 4) {
            const int gv = (pos == 0) ? v.x : (pos == 1) ? v.y
                         : (pos == 2) ? v.z : v.w;
            s_gt[0][mi] = gv;
            if (gv == 5) f5 = min(f5, (unsigned)mi);
            if (gv == 6) f6 = min(f6, (unsigned)mi);
        }
    }
    #pragma unroll
    for (int off = 32; off >= 1; off >>= 1) {
        f5 = min(f5, (unsigned)__shfl_xor((int)f5, off, 64));
        f6 = min(f6, (unsigned)__shfl_xor((int)f6, off, 64));
    }
    if ((tid & 63) == 0) {
        if (f5 != 0xFFFFFFFFu) atomicMin(&s_f[0], f5);
        if (f6 != 0xFFFFFFFFu) atomicMin(&s_f[1], f6);
    }
    __syncthreads();
    const unsigned f5_0 = s_f[0], f6_0 = s_f[1];

    // ---- Pipeline: issue row-1 loads, then emit row 0 under them ----
    int4 w[PASSES];
    #pragma unroll
    for (int p = 0; p < PASSES; ++p) {
        w[p] = row1[tid + p * BLOCK];      // line fetches proceed under stores
    }

    emit_row(s_gt[0], f5_0, f6_0, (int4*)(out + (size_t)b0 * SEQ_L * 8), tid);

    // ---- Row 1: consume + reduce ----
    f5 = 0xFFFFFFFFu; f6 = 0xFFFFFFFFu;
    #pragma unroll
    for (int p = 0; p < PASSES; ++p) {
        const int i4 = tid + p * BLOCK;
        const int j  = i4 * 4;
        const int mi  = (j + 10) / 11;
        const int pos = mi * 11 - j;
        if (pos < 4) {
            const int gv = (pos == 0) ? w[p].x : (pos == 1) ? w[p].y
                         : (pos == 2) ? w[p].z : w[p].w;
            s_gt[1][mi] = gv;
            if (gv == 5) f5 = min(f5, (unsigned)mi);
            if (gv == 6) f6 = min(f6, (unsigned)mi);
        }
    }
    #pragma unroll
    for (int off = 32; off >= 1; off >>= 1) {
        f5 = min(f5, (unsigned)__shfl_xor((int)f5, off, 64));
        f6 = min(f6, (unsigned)__shfl_xor((int)f6, off, 64));
    }
    if ((tid & 63) == 0) {
        if (f5 != 0xFFFFFFFFu) atomicMin(&s_f[2], f5);
        if (f6 != 0xFFFFFFFFu) atomicMin(&s_f[3], f6);
    }
    __syncthreads();

    emit_row(s_gt[1], s_f[2], s_f[3], (int4*)(out + (size_t)b1 * SEQ_L * 8), tid);
}

extern "C" void kernel_launch(void* const* d_in, const int* in_sizes, int n_in,
                              void* d_out, int out_size, void* d_ws, size_t ws_size,
                              hipStream_t stream) {
    const int* in = (const int*)d_in[0];
    int* out = (int*)d_out;
    const int batch = in_sizes[0] / (SEQ_L * NF);   // 1024
    mask_type_prob_kernel<<<batch / 2, BLOCK, 0, stream>>>(in, out);
}